// Round 1
// baseline (1139.587 us; speedup 1.0000x reference)
//
#include <hip/hip_runtime.h>

// Problem constants (from reference)
constexpr int N0 = 50000, N1 = 150000, N2 = 20000, N3 = 5000, N4 = 1000;
constexpr int E0 = 800000, E1 = 1500000, NNZ01 = 300000;
constexpr int D = 64;

// ---------------------------------------------------------------------------
// GEMM: y[n][64] = x[n][64] @ W[64][64]   (f32 vector ALU; no fp32 MFMA on CDNA4)
// 64-row tile per block, 256 threads, each thread 4 rows x 4 cols.
// ---------------------------------------------------------------------------
__global__ __launch_bounds__(256) void gemm64(const float* __restrict__ x,
                                              const float* __restrict__ W,
                                              float* __restrict__ y, int n) {
    __shared__ float Ws[64][64];
    __shared__ float Xs[64][64];
    const int t = threadIdx.x;
    for (int i = t; i < 64 * 64; i += 256) Ws[i >> 6][i & 63] = W[i];
    const long row0 = (long)blockIdx.x * 64;
    const int nrow = min(64, n - (int)row0);
    {
        const float4* xv = (const float4*)(x + row0 * D);
        float4* xs = (float4*)&Xs[0][0];
        for (int i = t; i < nrow * 16; i += 256) xs[i] = xv[i];
    }
    __syncthreads();
    const int r0 = (t >> 4) * 4;
    const int c  = (t & 15) * 4;
    float acc[4][4] = {};
#pragma unroll
    for (int k = 0; k < 64; ++k) {
        const float4 w = *(const float4*)&Ws[k][c];
#pragma unroll
        for (int rr = 0; rr < 4; ++rr) {
            const float xv = Xs[r0 + rr][k];
            acc[rr][0] = fmaf(xv, w.x, acc[rr][0]);
            acc[rr][1] = fmaf(xv, w.y, acc[rr][1]);
            acc[rr][2] = fmaf(xv, w.z, acc[rr][2]);
            acc[rr][3] = fmaf(xv, w.w, acc[rr][3]);
        }
    }
#pragma unroll
    for (int rr = 0; rr < 4; ++rr) {
        const long row = row0 + r0 + rr;
        if (row < n) {
            *(float4*)(y + row * D + c) =
                make_float4(acc[rr][0], acc[rr][1], acc[rr][2], acc[rr][3]);
        }
    }
}

// ---------------------------------------------------------------------------
// Aggregation GEMM: y = relu( (relu(A)+relu(B)) @ W )
// ---------------------------------------------------------------------------
__global__ __launch_bounds__(256) void gemm64_aggr(const float* __restrict__ A,
                                                   const float* __restrict__ B,
                                                   const float* __restrict__ W,
                                                   float* __restrict__ y, int n) {
    __shared__ float Ws[64][64];
    __shared__ float Xs[64][64];
    const int t = threadIdx.x;
    for (int i = t; i < 64 * 64; i += 256) Ws[i >> 6][i & 63] = W[i];
    const long row0 = (long)blockIdx.x * 64;
    const int nrow = min(64, n - (int)row0);
    {
        const float4* av = (const float4*)(A + row0 * D);
        const float4* bv = (const float4*)(B + row0 * D);
        float4* xs = (float4*)&Xs[0][0];
        for (int i = t; i < nrow * 16; i += 256) {
            const float4 p = av[i];
            const float4 q = bv[i];
            float4 r;
            r.x = fmaxf(p.x, 0.f) + fmaxf(q.x, 0.f);
            r.y = fmaxf(p.y, 0.f) + fmaxf(q.y, 0.f);
            r.z = fmaxf(p.z, 0.f) + fmaxf(q.z, 0.f);
            r.w = fmaxf(p.w, 0.f) + fmaxf(q.w, 0.f);
            xs[i] = r;
        }
    }
    __syncthreads();
    const int r0 = (t >> 4) * 4;
    const int c  = (t & 15) * 4;
    float acc[4][4] = {};
#pragma unroll
    for (int k = 0; k < 64; ++k) {
        const float4 w = *(const float4*)&Ws[k][c];
#pragma unroll
        for (int rr = 0; rr < 4; ++rr) {
            const float xv = Xs[r0 + rr][k];
            acc[rr][0] = fmaf(xv, w.x, acc[rr][0]);
            acc[rr][1] = fmaf(xv, w.y, acc[rr][1]);
            acc[rr][2] = fmaf(xv, w.z, acc[rr][2]);
            acc[rr][3] = fmaf(xv, w.w, acc[rr][3]);
        }
    }
#pragma unroll
    for (int rr = 0; rr < 4; ++rr) {
        const long row = row0 + r0 + rr;
        if (row < n) {
            float4 o;
            o.x = fmaxf(acc[rr][0], 0.f);
            o.y = fmaxf(acc[rr][1], 0.f);
            o.z = fmaxf(acc[rr][2], 0.f);
            o.w = fmaxf(acc[rr][3], 0.f);
            *(float4*)(y + row * D + c) = o;
        }
    }
}

// ---------------------------------------------------------------------------
// HBS edge scatter: acc[dst] += val*(cci@a) * m[src]   (one wave per edge)
// ---------------------------------------------------------------------------
__global__ __launch_bounds__(256) void hbs_scatter(const int* __restrict__ src,
                                                   const int* __restrict__ dst,
                                                   const float* __restrict__ val,
                                                   const float* __restrict__ cci,
                                                   const float* __restrict__ a,
                                                   const float* __restrict__ m,
                                                   float* __restrict__ acc, int ne) {
    const int e = blockIdx.x * 4 + (threadIdx.x >> 6);
    if (e >= ne) return;
    const int lane = threadIdx.x & 63;
    const int s = src[e];
    const int d = dst[e];
    const float coeff =
        val[e] * (cci[(size_t)e * 3 + 0] * a[0] + cci[(size_t)e * 3 + 1] * a[1] +
                  cci[(size_t)e * 3 + 2] * a[2]);
    atomicAdd(&acc[(size_t)d * D + lane], coeff * m[(size_t)s * D + lane]);
}

// ---------------------------------------------------------------------------
// HBNS edge scatter (both directions): acc10[row]+=v*ms[col]; acc01[col]+=v*mt[row]
// ---------------------------------------------------------------------------
__global__ __launch_bounds__(256) void hbns_scatter(const int* __restrict__ rowi,
                                                    const int* __restrict__ coli,
                                                    const float* __restrict__ val,
                                                    const float* __restrict__ ms,
                                                    const float* __restrict__ mt,
                                                    float* __restrict__ acc10,
                                                    float* __restrict__ acc01, int ne) {
    const int e = blockIdx.x * 4 + (threadIdx.x >> 6);
    if (e >= ne) return;
    const int lane = threadIdx.x & 63;
    const int r = rowi[e];
    const int c = coli[e];
    const float v = val[e];
    atomicAdd(&acc10[(size_t)r * D + lane], v * ms[(size_t)c * D + lane]);
    atomicAdd(&acc01[(size_t)c * D + lane], v * mt[(size_t)r * D + lane]);
}

extern "C" void kernel_launch(void* const* d_in, const int* in_sizes, int n_in,
                              void* d_out, int out_size, void* d_ws, size_t ws_size,
                              hipStream_t stream) {
    const float* x0    = (const float*)d_in[0];
    const float* x1    = (const float*)d_in[1];
    const float* x2    = (const float*)d_in[2];
    const float* x3    = (const float*)d_in[3];
    const float* x4    = (const float*)d_in[4];
    const int*   adj0  = (const int*)d_in[5];
    const float* adj0v = (const float*)d_in[6];
    const int*   adj1  = (const int*)d_in[7];
    const float* adj1v = (const float*)d_in[8];
    const int*   inc01 = (const int*)d_in[9];
    const float* incv  = (const float*)d_in[10];
    const float* cci0  = (const float*)d_in[11];
    const float* cci1  = (const float*)d_in[12];
    const float* Whbs0 = (const float*)d_in[13];
    const float* ahbs0 = (const float*)d_in[14];
    const float* Whbs1 = (const float*)d_in[15];
    const float* ahbs1 = (const float*)d_in[16];
    const float* Wns_s = (const float*)d_in[17];
    const float* Wns_t = (const float*)d_in[18];
    const float* Wagg0 = (const float*)d_in[19];
    const float* Wagg1 = (const float*)d_in[20];

    float* out = (float*)d_out;
    float* ws  = (float*)d_ws;

    const size_t S0 = (size_t)N0 * D;  // 3.2M floats
    const size_t S1 = (size_t)N1 * D;  // 9.6M floats

    // Scratch layout. Full layout needs (2*S0+2*S1)*2 floats = 204.8 MB.
    // Fallback stages m0/m1 inside d_out (dead by the time aggr GEMMs write it).
    const size_t full_bytes = (2 * S0 + 2 * S1) * 2 * sizeof(float);
    float *m0, *m1, *msb, *mtb, *acc00, *acc11, *acc10, *acc01;
    if (ws_size >= full_bytes) {
        m0 = ws;            m1 = m0 + S0;
        msb = m1 + S1;      mtb = msb + S1;
        acc00 = mtb + S0;   acc11 = acc00 + S0;
        acc10 = acc11 + S1; acc01 = acc10 + S0;
    } else {
        m0 = out;           m1 = out + S0;          // in d_out (overwritten later)
        msb = ws;           mtb = msb + S1;
        acc00 = mtb + S0;   acc11 = acc00 + S0;
        acc10 = acc11 + S1; acc01 = acc10 + S0;
    }

    // Zero all four accumulators (contiguous in both layouts)
    hipMemsetAsync(acc00, 0, (2 * S0 + 2 * S1) * sizeof(float), stream);

    // Dense projections
    gemm64<<<(N0 + 63) / 64, 256, 0, stream>>>(x0, Whbs0, m0, N0);
    gemm64<<<(N1 + 63) / 64, 256, 0, stream>>>(x1, Whbs1, m1, N1);
    gemm64<<<(N1 + 63) / 64, 256, 0, stream>>>(x1, Wns_s, msb, N1);
    gemm64<<<(N0 + 63) / 64, 256, 0, stream>>>(x0, Wns_t, mtb, N0);

    // Edge scatters (atomic segment sums)
    hbs_scatter<<<(E0 + 3) / 4, 256, 0, stream>>>(adj0, adj0 + E0, adj0v, cci0,
                                                  ahbs0, m0, acc00, E0);
    hbs_scatter<<<(E1 + 3) / 4, 256, 0, stream>>>(adj1, adj1 + E1, adj1v, cci1,
                                                  ahbs1, m1, acc11, E1);
    hbns_scatter<<<(NNZ01 + 3) / 4, 256, 0, stream>>>(inc01, inc01 + NNZ01, incv,
                                                      msb, mtb, acc10, acc01, NNZ01);

    // Aggregation GEMMs (relu(a)+relu(b) fused on load, relu on store)
    gemm64_aggr<<<(N0 + 63) / 64, 256, 0, stream>>>(acc00, acc10, Wagg0, out, N0);
    gemm64_aggr<<<(N1 + 63) / 64, 256, 0, stream>>>(acc11, acc01, Wagg1, out + S0, N1);

    // Pass-through outputs
    hipMemcpyAsync(out + S0 + S1, x2, (size_t)N2 * D * sizeof(float),
                   hipMemcpyDeviceToDevice, stream);
    hipMemcpyAsync(out + S0 + S1 + (size_t)N2 * D, x3, (size_t)N3 * D * sizeof(float),
                   hipMemcpyDeviceToDevice, stream);
    hipMemcpyAsync(out + S0 + S1 + (size_t)(N2 + N3) * D, x4,
                   (size_t)N4 * D * sizeof(float), hipMemcpyDeviceToDevice, stream);
}

// Round 2
// 1106.003 us; speedup vs baseline: 1.0304x; 1.0304x over previous
//
#include <hip/hip_runtime.h>

// Problem constants (from reference)
constexpr int N0 = 50000, N1 = 150000, N2 = 20000, N3 = 5000, N4 = 1000;
constexpr int E0 = 800000, E1 = 1500000, NNZ01 = 300000;
constexpr int D = 64;

constexpr int TOT_NODES = 2 * N0 + 2 * N1;      // concatenated segment-count space
constexpr int OFFN = TOT_NODES + 1;             // +1 tail for exclusive-scan total
constexpr int SCAN_CHUNK = 2048;                // 256 threads x 8
constexpr int NB = (OFFN + SCAN_CHUNK - 1) / SCAN_CHUNK;  // 196 scan blocks

// ---------------------------------------------------------------------------
// GEMM: y[n][64] = x[n][64] @ W[64][64]  (f32 vector ALU; no fp32 MFMA on CDNA4)
// 64-row tile per block, 256 threads, each thread 4 rows x 4 cols.
// Safe to run in-place (y == x): each block reads only the rows it writes,
// and all reads complete (into LDS + __syncthreads) before any write.
// ---------------------------------------------------------------------------
template <bool RELU_STORE>
__global__ __launch_bounds__(256) void gemm64(const float* __restrict__ x,
                                              const float* __restrict__ W,
                                              float* __restrict__ y, int n) {
    __shared__ float Ws[64][64];
    __shared__ float Xs[64][64];
    const int t = threadIdx.x;
    for (int i = t; i < 64 * 64; i += 256) Ws[i >> 6][i & 63] = W[i];
    const long row0 = (long)blockIdx.x * 64;
    const int nrow = min(64, n - (int)row0);
    {
        const float4* xv = (const float4*)(x + row0 * D);
        float4* xs = (float4*)&Xs[0][0];
        for (int i = t; i < nrow * 16; i += 256) xs[i] = xv[i];
    }
    __syncthreads();
    const int r0 = (t >> 4) * 4;
    const int c  = (t & 15) * 4;
    float acc[4][4] = {};
#pragma unroll
    for (int k = 0; k < 64; ++k) {
        const float4 w = *(const float4*)&Ws[k][c];
#pragma unroll
        for (int rr = 0; rr < 4; ++rr) {
            const float xv = Xs[r0 + rr][k];
            acc[rr][0] = fmaf(xv, w.x, acc[rr][0]);
            acc[rr][1] = fmaf(xv, w.y, acc[rr][1]);
            acc[rr][2] = fmaf(xv, w.z, acc[rr][2]);
            acc[rr][3] = fmaf(xv, w.w, acc[rr][3]);
        }
    }
#pragma unroll
    for (int rr = 0; rr < 4; ++rr) {
        const long row = row0 + r0 + rr;
        if (row < n) {
            float4 o = make_float4(acc[rr][0], acc[rr][1], acc[rr][2], acc[rr][3]);
            if (RELU_STORE) {
                o.x = fmaxf(o.x, 0.f); o.y = fmaxf(o.y, 0.f);
                o.z = fmaxf(o.z, 0.f); o.w = fmaxf(o.w, 0.f);
            }
            *(float4*)(y + row * D + c) = o;
        }
    }
}

// ---------------------------------------------------------------------------
// HBS prep: coeff[e] = val[e] * (cci[e] . a); histogram destination counts.
// ---------------------------------------------------------------------------
__global__ __launch_bounds__(256) void hbs_prep(const int* __restrict__ dst,
                                                const float* __restrict__ val,
                                                const float* __restrict__ cci,
                                                const float* __restrict__ a,
                                                float* __restrict__ coeff,
                                                int* __restrict__ cnt, int ne) {
    const float a0 = a[0], a1 = a[1], a2 = a[2];
    for (int e = blockIdx.x * 256 + threadIdx.x; e < ne; e += gridDim.x * 256) {
        const size_t b = (size_t)e * 3;
        coeff[e] = val[e] * (cci[b] * a0 + cci[b + 1] * a1 + cci[b + 2] * a2);
        atomicAdd(&cnt[dst[e]], 1);
    }
}

// Histogram both directions of the incidence matrix.
__global__ __launch_bounds__(256) void hist2(const int* __restrict__ row,
                                             const int* __restrict__ col,
                                             int* __restrict__ cntA,
                                             int* __restrict__ cntB, int ne) {
    for (int e = blockIdx.x * 256 + threadIdx.x; e < ne; e += gridDim.x * 256) {
        atomicAdd(&cntA[row[e]], 1);
        atomicAdd(&cntB[col[e]], 1);
    }
}

// ---------------------------------------------------------------------------
// Exclusive prefix scan over OFFN ints (3-kernel), in-place on `data`.
// ---------------------------------------------------------------------------
__global__ __launch_bounds__(256) void scan1(int* __restrict__ data,
                                             int* __restrict__ bsum, int n) {
    __shared__ int lds[256];
    const int t = threadIdx.x;
    const int base = blockIdx.x * SCAN_CHUNK + t * 8;
    int v[8]; int tot = 0;
#pragma unroll
    for (int j = 0; j < 8; ++j) {
        const int i = base + j;
        const int x = (i < n) ? data[i] : 0;
        v[j] = tot; tot += x;
    }
    lds[t] = tot;
    __syncthreads();
    for (int off = 1; off < 256; off <<= 1) {
        const int y = (t >= off) ? lds[t - off] : 0;
        __syncthreads();
        lds[t] += y;
        __syncthreads();
    }
    const int excl = lds[t] - tot;
    if (t == 255) bsum[blockIdx.x] = lds[255];
#pragma unroll
    for (int j = 0; j < 8; ++j) {
        const int i = base + j;
        if (i < n) data[i] = excl + v[j];
    }
}

__global__ __launch_bounds__(256) void scan2(int* __restrict__ bsum, int nb) {
    __shared__ int lds[256];
    const int t = threadIdx.x;
    const int x = (t < nb) ? bsum[t] : 0;
    lds[t] = x;
    __syncthreads();
    for (int off = 1; off < 256; off <<= 1) {
        const int y = (t >= off) ? lds[t - off] : 0;
        __syncthreads();
        lds[t] += y;
        __syncthreads();
    }
    if (t < nb) bsum[t] = lds[t] - x;
}

__global__ __launch_bounds__(256) void scan3(int* __restrict__ data,
                                             const int* __restrict__ bsum, int n) {
    const int add = bsum[blockIdx.x];
    const int base = blockIdx.x * SCAN_CHUNK + threadIdx.x * 8;
#pragma unroll
    for (int j = 0; j < 8; ++j) {
        const int i = base + j;
        if (i < n) data[i] += add;
    }
}

// ---------------------------------------------------------------------------
// Reorder: place edge ids grouped by destination (counting-sort scatter).
// ---------------------------------------------------------------------------
__global__ __launch_bounds__(256) void reorder1(const int* __restrict__ dst,
                                                int* __restrict__ cursor,
                                                int* __restrict__ order, int ne) {
    for (int e = blockIdx.x * 256 + threadIdx.x; e < ne; e += gridDim.x * 256) {
        const int pos = atomicAdd(&cursor[dst[e]], 1);
        order[pos] = e;
    }
}

__global__ __launch_bounds__(256) void reorder2(const int* __restrict__ row,
                                                const int* __restrict__ col,
                                                int* __restrict__ curA,
                                                int* __restrict__ curB,
                                                int* __restrict__ order, int ne) {
    for (int e = blockIdx.x * 256 + threadIdx.x; e < ne; e += gridDim.x * 256) {
        const int pA = atomicAdd(&curA[row[e]], 1);
        order[pA] = e;
        const int pB = atomicAdd(&curB[col[e]], 1);
        order[pB] = e;
    }
}

// ---------------------------------------------------------------------------
// Segment accumulate (gather): one wave per destination node, lane = feature.
// Lane-parallel meta prefetch (64 edges at a time) + __shfl broadcast.
// Writes relu(sum); ADD variant accumulates onto existing buffer.
// ---------------------------------------------------------------------------
template <bool ADD>
__global__ __launch_bounds__(256) void seg_accum(const int* __restrict__ order,
                                                 const int* __restrict__ offsets,
                                                 const int* __restrict__ src,
                                                 const float* __restrict__ coeff,
                                                 const float* __restrict__ m,
                                                 float* __restrict__ outbuf, int n) {
    const int node = blockIdx.x * 4 + (threadIdx.x >> 6);
    if (node >= n) return;
    const int lane = threadIdx.x & 63;
    const int beg = offsets[node];
    const int end = offsets[node + 1];
    float acc = 0.f;
    for (int base = beg; base < end; base += 64) {
        const int nn = min(64, end - base);
        int s_l = 0; float c_l = 0.f;
        if (lane < nn) {
            const int eid = order[base + lane];
            s_l = src[eid];
            c_l = coeff[eid];
        }
        for (int j = 0; j < nn; ++j) {
            const int s = __shfl(s_l, j);
            const float c = __shfl(c_l, j);
            acc = fmaf(c, m[(size_t)s * D + lane], acc);
        }
    }
    const float r = fmaxf(acc, 0.f);
    float* o = outbuf + (size_t)node * D + lane;
    if (ADD) *o += r; else *o = r;
}

extern "C" void kernel_launch(void* const* d_in, const int* in_sizes, int n_in,
                              void* d_out, int out_size, void* d_ws, size_t ws_size,
                              hipStream_t stream) {
    const float* x0    = (const float*)d_in[0];
    const float* x1    = (const float*)d_in[1];
    const float* x2    = (const float*)d_in[2];
    const float* x3    = (const float*)d_in[3];
    const float* x4    = (const float*)d_in[4];
    const int*   adj0  = (const int*)d_in[5];   // [2][E0]: row 0 = src, row 1 = dst
    const float* adj0v = (const float*)d_in[6];
    const int*   adj1  = (const int*)d_in[7];   // [2][E1]
    const float* adj1v = (const float*)d_in[8];
    const int*   inc01 = (const int*)d_in[9];   // [2][NNZ01]: row 0 = n0-id, row 1 = n1-id
    const float* incv  = (const float*)d_in[10];
    const float* cci0  = (const float*)d_in[11];
    const float* cci1  = (const float*)d_in[12];
    const float* Whbs0 = (const float*)d_in[13];
    const float* ahbs0 = (const float*)d_in[14];
    const float* Whbs1 = (const float*)d_in[15];
    const float* ahbs1 = (const float*)d_in[16];
    const float* Wns_s = (const float*)d_in[17];
    const float* Wns_t = (const float*)d_in[18];
    const float* Wagg0 = (const float*)d_in[19];
    const float* Wagg1 = (const float*)d_in[20];

    float* out = (float*)d_out;

    const size_t S0 = (size_t)N0 * D;  // 3.2M floats
    const size_t S1 = (size_t)N1 * D;  // 9.6M floats

    // ---- workspace layout (floats/ints, 4B each); total ~126.5 MB ----
    float* m0     = (float*)d_ws;            // S0
    float* m1     = m0 + S0;                 // S1
    float* msb    = m1 + S1;                 // S1
    float* mtb    = msb + S1;                // S0
    float* coeff0 = mtb + S0;                // E0
    float* coeff1 = coeff0 + E0;             // E1
    int*   offs   = (int*)(coeff1 + E1);     // OFFN
    int*   bsum   = offs + OFFN;             // NB (pad to 256)
    int*   cursor = bsum + 256;              // TOT_NODES
    int*   order  = cursor + TOT_NODES;      // E0 + E1 + 2*NNZ01

    // s00/s11 live in d_out; aggregation GEMM runs in-place on them.
    float* s00 = out;
    float* s11 = out + S0;

    // offsets-count space must start zeroed (ws is poisoned before every call)
    hipMemsetAsync(offs, 0, OFFN * sizeof(int), stream);

    // Dense projections
    gemm64<false><<<(N0 + 63) / 64, 256, 0, stream>>>(x0, Whbs0, m0, N0);
    gemm64<false><<<(N1 + 63) / 64, 256, 0, stream>>>(x1, Whbs1, m1, N1);
    gemm64<false><<<(N1 + 63) / 64, 256, 0, stream>>>(x1, Wns_s, msb, N1);
    gemm64<false><<<(N0 + 63) / 64, 256, 0, stream>>>(x0, Wns_t, mtb, N0);

    // Per-edge coefficients + destination histograms (concatenated count space:
    // [0,N0) hbs0 | [N0,N0+N1) hbs1 | [N0+N1,2N0+N1) hbns rows | [2N0+N1,TOT) hbns cols)
    hbs_prep<<<1024, 256, 0, stream>>>(adj0 + E0, adj0v, cci0, ahbs0, coeff0,
                                       offs, E0);
    hbs_prep<<<2048, 256, 0, stream>>>(adj1 + E1, adj1v, cci1, ahbs1, coeff1,
                                       offs + N0, E1);
    hist2<<<1024, 256, 0, stream>>>(inc01, inc01 + NNZ01, offs + N0 + N1,
                                    offs + 2 * N0 + N1, NNZ01);

    // Exclusive scan (in-place) -> global offsets into the shared order buffer
    scan1<<<NB, 256, 0, stream>>>(offs, bsum, OFFN);
    scan2<<<1, 256, 0, stream>>>(bsum, NB);
    scan3<<<NB, 256, 0, stream>>>(offs, bsum, OFFN);

    // Counting-sort scatter of edge ids, grouped by destination
    hipMemcpyAsync(cursor, offs, TOT_NODES * sizeof(int),
                   hipMemcpyDeviceToDevice, stream);
    reorder1<<<1024, 256, 0, stream>>>(adj0 + E0, cursor, order, E0);
    reorder1<<<2048, 256, 0, stream>>>(adj1 + E1, cursor + N0, order, E1);
    reorder2<<<1024, 256, 0, stream>>>(inc01, inc01 + NNZ01, cursor + N0 + N1,
                                       cursor + 2 * N0 + N1, order, NNZ01);

    // Gather-based segment sums (atomic-free), relu fused, second term added
    seg_accum<false><<<(N0 + 3) / 4, 256, 0, stream>>>(order, offs, adj0, coeff0,
                                                       m0, s00, N0);
    seg_accum<false><<<(N1 + 3) / 4, 256, 0, stream>>>(order, offs + N0, adj1,
                                                       coeff1, m1, s11, N1);
    seg_accum<true><<<(N0 + 3) / 4, 256, 0, stream>>>(order, offs + N0 + N1,
                                                      inc01 + NNZ01, incv, msb,
                                                      s00, N0);
    seg_accum<true><<<(N1 + 3) / 4, 256, 0, stream>>>(order, offs + 2 * N0 + N1,
                                                      inc01, incv, mtb, s11, N1);

    // Aggregation GEMMs, in-place on d_out (relu on store)
    gemm64<true><<<(N0 + 63) / 64, 256, 0, stream>>>(s00, Wagg0, out, N0);
    gemm64<true><<<(N1 + 63) / 64, 256, 0, stream>>>(s11, Wagg1, out + S0, N1);

    // Pass-through outputs
    hipMemcpyAsync(out + S0 + S1, x2, (size_t)N2 * D * sizeof(float),
                   hipMemcpyDeviceToDevice, stream);
    hipMemcpyAsync(out + S0 + S1 + (size_t)N2 * D, x3, (size_t)N3 * D * sizeof(float),
                   hipMemcpyDeviceToDevice, stream);
    hipMemcpyAsync(out + S0 + S1 + (size_t)(N2 + N3) * D, x4,
                   (size_t)N4 * D * sizeof(float), hipMemcpyDeviceToDevice, stream);
}